// Round 17
// baseline (303.678 us; speedup 1.0000x reference)
//
#include <hip/hip_runtime.h>
#include <hip/hip_bf16.h>

#define BB 8
#define NN 16384
#define DD 1024
#define AA 128
#define ROWS 64
#define NBLKS (BB * NN / ROWS)   // 2048

typedef __attribute__((ext_vector_type(8))) short bf16x8;
typedef __attribute__((ext_vector_type(4))) float f32x4;
typedef __attribute__((ext_vector_type(4))) unsigned short u16x4;

__device__ __forceinline__ unsigned short f2bf(float x) {
  union { __hip_bfloat16 h; unsigned short u; } cv;
  cv.h = __float2bfloat16(x);
  return cv.u;
}

__device__ __forceinline__ float softplusf(float x) {
  return fmaxf(x, 0.f) + log1pf(expf(-fabsf(x)));
}

// order-preserving float->uint map (monotone)
__device__ __forceinline__ unsigned int ordu(float x) {
  unsigned int u = __float_as_uint(x);
  return (u & 0x80000000u) ? ~u : (u | 0x80000000u);
}

// LDS index swizzle for k_select
__device__ __forceinline__ int fvx(int i) {
  return i ^ ((i >> 6) & 63);
}

// async global->LDS DMA, 16 B per lane; dest resolves to wave base + lane*16
__device__ __forceinline__ void gload16(const void* g, void* l) {
  __builtin_amdgcn_global_load_lds(
      (const __attribute__((address_space(1))) unsigned int*)g,
      (__attribute__((address_space(3))) unsigned int*)l, 16, 0, 0);
}

// ---------------------------------------------------------------------------
// Kernel 0: W1 -> W1Ts bf16 panels (linear image == swizzled Bs layout);
// zero out[8..9].
// ---------------------------------------------------------------------------
__global__ __launch_bounds__(256) void k_prep(
    const float* __restrict__ W1, unsigned short* __restrict__ W1Ts,
    float* __restrict__ out) {
  const int gid = blockIdx.x * 256 + threadIdx.x;
  if (gid == 0) { out[8] = 0.f; out[9] = 0.f; }
  if (gid < DD * AA) {
    const int k = gid >> 7, col = gid & 127;
    const int kp = k >> 6, kin = k & 63;
    const int g = kin >> 3, j = kin & 7;
    W1Ts[kp * 8192 + col * 64 + ((g ^ (col & 7)) << 3) + j] =
        f2bf(W1[k * AA + col]);
  }
}

// ---------------------------------------------------------------------------
// Kernel 1: f[n] = b2 + sum_a w2[a] tanh((X W1)[n][a] + b1[a]); y[n]=X[n].Wc
// R16 structure + A-prefetch: A(st+1) register loads issue AFTER the first
// barrier so HBM latency hides under MFMA(st); consumed (yp+cvt+ds_write) at
// the top of st+1. B stays gload_lds DMA (zero register cost).
// ---------------------------------------------------------------------------
__global__ __launch_bounds__(256) void k_scores(
    const float* __restrict__ X, const unsigned short* __restrict__ W1Ts,
    const float* __restrict__ b1, const float* __restrict__ w2,
    const float* __restrict__ b2p, const float* __restrict__ Wc,
    float* __restrict__ f, float* __restrict__ y) {
  __shared__ unsigned short As[ROWS * 64];   // 8 KB, [row][k] bf16 swizzled
  __shared__ unsigned short Bs[128 * 64];    // 16 KB, [col][k] swizzled image
  const int t = threadIdx.x;
  const int lane = t & 63;
  const int wv = t >> 6;
  const int l15 = lane & 15, lg = lane >> 4;
  const size_t row0 = (size_t)blockIdx.x * ROWS;
  const float* Xb = X + row0 * DD;

  f32x4 zero4 = {0.f, 0.f, 0.f, 0.f};
  f32x4 acc[8];
#pragma unroll
  for (int ni = 0; ni < 8; ++ni) acc[ni] = zero4;

  float yp[4];
#pragma unroll
  for (int j = 0; j < 4; ++j) yp[j] = 0.f;

  const int kq = (t & 15) * 4;
  const int rbase = t >> 4;                  // 0..15

  // ---- prologue: A(0) register loads ----
  float4 a_[4];
  float4 wc4;
#pragma unroll
  for (int j = 0; j < 4; ++j)
    a_[j] = *(const float4*)(Xb + (size_t)(rbase + j * 16) * DD + kq);
  wc4 = *(const float4*)(Wc + kq);

  for (int stp = 0; stp < 16; ++stp) {
    // ---- B: linear DMA of the pre-swizzled 16 KB panel ----
    {
      const unsigned short* Pp = W1Ts + stp * 8192;
#pragma unroll
      for (int q = 0; q < 4; ++q)
        gload16(Pp + ((wv * 4 + q) * 64 + lane) * 8,
                &Bs[((wv * 4 + q) * 64 + lane) * 8]);
    }
    // ---- consume A(stp) regs: yp + cvt + swizzled ds_write ----
#pragma unroll
    for (int j = 0; j < 4; ++j) {
      const int r = rbase + j * 16;
      yp[j] += a_[j].x * wc4.x + a_[j].y * wc4.y +
               a_[j].z * wc4.z + a_[j].w * wc4.w;
      u16x4 p;
      p.x = f2bf(a_[j].x); p.y = f2bf(a_[j].y);
      p.z = f2bf(a_[j].z); p.w = f2bf(a_[j].w);
      const int idx = r * 64 + (((kq >> 3) ^ (r & 7)) << 3) + (kq & 7);
      *(u16x4*)&As[idx] = p;
    }
    __syncthreads();
    // ---- prefetch A(stp+1): latency hides under the MFMA phase below ----
    if (stp < 15) {
      const int k0n = (stp + 1) * 64;
#pragma unroll
      for (int j = 0; j < 4; ++j)
        a_[j] = *(const float4*)(Xb + (size_t)(rbase + j * 16) * DD + k0n + kq);
      wc4 = *(const float4*)(Wc + k0n + kq);
    }
    // ---- MFMA: wave covers rows wv*16..+15 x all 128 cols ----
    const int r = wv * 16 + l15;
    const int rx = r & 7;
#pragma unroll
    for (int ks = 0; ks < 2; ++ks) {
      const int chunk = ks * 4 + lg;
      const bf16x8 af = *(const bf16x8*)&As[r * 64 + ((chunk ^ rx) << 3)];
#pragma unroll
      for (int ni = 0; ni < 8; ++ni) {
        const int c = ni * 16 + l15;
        const bf16x8 bg =
            *(const bf16x8*)&Bs[c * 64 + ((chunk ^ (c & 7)) << 3)];
        acc[ni] = __builtin_amdgcn_mfma_f32_16x16x32_bf16(af, bg, acc[ni], 0, 0, 0);
      }
    }
    __syncthreads();
  }

  // y: reduce yp[j] across the 16 lanes sharing each row
#pragma unroll
  for (int j = 0; j < 4; ++j) {
    float s = yp[j];
    s += __shfl_xor(s, 1);
    s += __shfl_xor(s, 2);
    s += __shfl_xor(s, 4);
    s += __shfl_xor(s, 8);
    if ((t & 15) == 0) y[row0 + rbase + j * 16] = s;
  }

  // f epilogue: wave-local; C row = lg*4+q (global wv*16+...), col = ni*16+l15
  const float b2 = b2p[0];
  float w2c[8], b1c[8];
#pragma unroll
  for (int ni = 0; ni < 8; ++ni) {
    w2c[ni] = w2[ni * 16 + l15];
    b1c[ni] = b1[ni * 16 + l15];
  }
#pragma unroll
  for (int q = 0; q < 4; ++q) {
    float s = 0.f;
#pragma unroll
    for (int ni = 0; ni < 8; ++ni)
      s += w2c[ni] * tanhf(acc[ni][q] + b1c[ni]);
    s += __shfl_xor(s, 1);
    s += __shfl_xor(s, 2);
    s += __shfl_xor(s, 4);
    s += __shfl_xor(s, 8);
    if (l15 == 0) f[row0 + wv * 16 + lg * 4 + q] = s + b2;
  }
}

// ---------------------------------------------------------------------------
// Kernel 2 (fused select+final): 16 blocks = (bag b, mode).
//   mode 0: bag stats (bag_pred, crit_loss) + top-64 + top-in + out losses
//   mode 1: bottom-64 + bottom-in losses
// Radix select with wave-private histograms; selected ids kept in LDS.
// ---------------------------------------------------------------------------
__global__ __launch_bounds__(1024) void k_select(
    const float* __restrict__ f, const float* __restrict__ y,
    const float* __restrict__ mask, const int* __restrict__ labels,
    const float* __restrict__ bc, const float* __restrict__ X,
    const float* __restrict__ Wi, const float* __restrict__ bi,
    float* __restrict__ out) {
  __shared__ unsigned int uv[NN];          // 64 KB, swizzled via fvx()
  __shared__ unsigned int whist[16][256];  // 16 KB wave-private hists
  __shared__ unsigned int selL[64];
  __shared__ unsigned int wq[4];
  __shared__ unsigned int sb[4];
  __shared__ float redf[16];
  __shared__ float redo[16];
  const int t = threadIdx.x;
  const int lane = t & 63, w = t >> 6;
  const int b = blockIdx.x >> 1;
  const int mode = blockIdx.x & 1;
  const float* fb = f + (size_t)b * NN;
  const float* yb = y + (size_t)b * NN;
  const float* kb = mask + (size_t)b * NN;

  if (mode == 0) {
    float mx = -3.0e38f;
    for (int i = t; i < NN; i += 1024) {
      const float v = fb[i];
      uv[fvx(i)] = ordu(v);
      mx = fmaxf(mx, kb[i] > 0.f ? v : -1.0e30f);
    }
#pragma unroll
    for (int s = 1; s < 64; s <<= 1) mx = fmaxf(mx, __shfl_xor(mx, s));
    if (lane == 0) redf[w] = mx;
    __syncthreads();
    float m = redf[0];
#pragma unroll
    for (int q = 1; q < 16; ++q) m = fmaxf(m, redf[q]);
    __syncthreads();

    float se = 0.f, sy = 0.f;
    for (int i = t; i < NN; i += 1024) {
      if (kb[i] > 0.f) {
        const float e = expf(fb[i] - m);
        se += e;
        sy += e * yb[i];
      }
    }
#pragma unroll
    for (int s = 1; s < 64; s <<= 1) se += __shfl_xor(se, s);
    if (lane == 0) redf[w] = se;
    __syncthreads();
    float Z = 0.f;
#pragma unroll
    for (int q = 0; q < 16; ++q) Z += redf[q];
    __syncthreads();
#pragma unroll
    for (int s = 1; s < 64; s <<= 1) sy += __shfl_xor(sy, s);
    if (lane == 0) redf[w] = sy;
    __syncthreads();
    if (t == 0) {
      float Sy = 0.f;
#pragma unroll
      for (int q = 0; q < 16; ++q) Sy += redf[q];
      const float bp = Sy / Z + bc[0];
      out[b] = bp;
      const float lf = (float)labels[b];
      atomicAdd(out + 8, (softplusf(bp) - bp * lf) * 0.125f);
    }
  } else {
    for (int i = t; i < NN; i += 1024) uv[fvx(i)] = ~ordu(fb[i]);
  }
  __syncthreads();

  // 4-pass byte radix select for the 64 largest keys (ties: lowest index)
  const int i0 = t * 16;
  unsigned int pref = 0u, above = 0u, krem = 64u;
  for (int p = 3; p >= 0; --p) {
    for (int q = t; q < 4096; q += 1024) ((unsigned int*)whist)[q] = 0u;
    __syncthreads();
    const unsigned int pmask = (p == 3) ? 0u : (0xFFFFFFFFu << ((p + 1) * 8));
    for (int j = 0; j < 16; ++j) {
      const unsigned int u = uv[fvx(i0 + j)];
      if ((u & pmask) == pref)
        atomicAdd(&whist[w][(u >> (p * 8)) & 255u], 1u);
    }
    __syncthreads();
    unsigned int v = 0, s = 0;
    if (t < 256) {
#pragma unroll
      for (int q = 0; q < 16; ++q) v += whist[q][t];
      s = v;
#pragma unroll
      for (int off = 1; off < 64; off <<= 1) {
        const unsigned int o = __shfl_down(s, off);
        if (lane + off < 64) s += o;
      }
      if (lane == 0) wq[w] = s;
    }
    __syncthreads();
    if (t < 256) {
      unsigned int hi = 0;
      for (int q = w + 1; q < 4; ++q) hi += wq[q];
      const unsigned int Ssuf = s + hi;
      const unsigned int Snext = Ssuf - v;
      if (Ssuf >= krem && Snext < krem) {
        sb[0] = pref | ((unsigned int)t << (p * 8));
        sb[1] = above + Snext;
        sb[2] = krem - Snext;
        sb[3] = 0u;
      }
    }
    __syncthreads();
    pref = sb[0]; above = sb[1]; krem = sb[2];
  }
  unsigned int myt = 0;
  for (int j = 0; j < 16; ++j) {
    const unsigned int u = uv[fvx(i0 + j)];
    if (u > pref) {
      const unsigned int pos = atomicAdd(&sb[3], 1u);
      selL[pos] = i0 + j;
    } else if (u == pref) {
      myt++;
    }
  }
  unsigned int pv = myt;
#pragma unroll
  for (int o2 = 1; o2 < 64; o2 <<= 1) {
    const unsigned int o = __shfl_up(pv, o2);
    if (lane >= o2) pv += o;
  }
  __syncthreads();
  if (lane == 63) ((unsigned int*)whist)[w] = pv;   // reuse whist
  __syncthreads();
  unsigned int base = 0;
  for (int q = 0; q < w; ++q) base += ((unsigned int*)whist)[q];
  unsigned int gg = base + pv - myt;
  for (int j = 0; j < 16 && myt > 0; ++j) {
    const unsigned int u = uv[fvx(i0 + j)];
    if (u == pref) {
      if (gg < krem) selL[above + gg] = i0 + j;
      gg++;
      myt--;
    }
  }
  __syncthreads();

  // ---- fused instance losses for this block's 64 rows ----
  const int label = labels[b];
  const float* Win = Wi + label * (DD * 2);
  const float* Wot = Wi + (1 - label) * (DD * 2);
  const float bin0 = bi[label * 2], bin1 = bi[label * 2 + 1];
  const float bo0 = bi[(1 - label) * 2], bo1 = bi[(1 - label) * 2 + 1];
  float ain = 0.f, aout = 0.f;
  for (int rr = w; rr < 64; rr += 16) {     // 4 rows per wave
    const int id = selL[rr];
    const float* xr = X + ((size_t)b * NN + id) * DD;
    float p0 = 0.f, p1 = 0.f, p2 = 0.f, p3 = 0.f;
#pragma unroll
    for (int j = 0; j < 16; j += 4) {
      const int d = lane * 16 + j;
      const float4 x = *(const float4*)(xr + d);
      const float4 wa = *(const float4*)(Win + d * 2);
      const float4 wb = *(const float4*)(Win + d * 2 + 4);
      p0 += x.x * wa.x + x.y * wa.z + x.z * wb.x + x.w * wb.z;
      p1 += x.x * wa.y + x.y * wa.w + x.z * wb.y + x.w * wb.w;
      if (mode == 0) {
        const float4 oa = *(const float4*)(Wot + d * 2);
        const float4 ob = *(const float4*)(Wot + d * 2 + 4);
        p2 += x.x * oa.x + x.y * oa.z + x.z * ob.x + x.w * ob.z;
        p3 += x.x * oa.y + x.y * oa.w + x.z * ob.y + x.w * ob.w;
      }
    }
#pragma unroll
    for (int sh = 1; sh < 64; sh <<= 1) {
      p0 += __shfl_xor(p0, sh);
      p1 += __shfl_xor(p1, sh);
      p2 += __shfl_xor(p2, sh);
      p3 += __shfl_xor(p3, sh);
    }
    if (lane == 0) {
      const float l0 = p0 + bin0, l1 = p1 + bin1;
      if (mode == 0) {
        ain += softplusf(l0 + 1.f - l1);              // top, target 1
        aout += softplusf((p3 + bo1) + 1.f - (p2 + bo0));  // out, target 0
      } else {
        ain += softplusf(l1 + 1.f - l0);              // bottom, target 0
      }
    }
  }
  if (lane == 0) { redf[w] = ain; redo[w] = aout; }
  __syncthreads();
  if (t == 0) {
    float ti = 0.f, to = 0.f;
#pragma unroll
    for (int q = 0; q < 16; ++q) { ti += redf[q]; to += redo[q]; }
    atomicAdd(out + 9, ti * (1.0f / 128.0f) + to * (1.0f / 64.0f));
  }
}

// ---------------------------------------------------------------------------

extern "C" void kernel_launch(void* const* d_in, const int* in_sizes, int n_in,
                              void* d_out, int out_size, void* d_ws, size_t ws_size,
                              hipStream_t stream) {
  const float* X      = (const float*)d_in[0];
  const float* mask   = (const float*)d_in[1];
  const int*   labels = (const int*)d_in[2];
  const float* W1     = (const float*)d_in[3];
  const float* b1     = (const float*)d_in[4];
  const float* w2     = (const float*)d_in[5];
  const float* b2     = (const float*)d_in[6];
  const float* Wc     = (const float*)d_in[7];
  const float* bc     = (const float*)d_in[8];
  const float* Wi     = (const float*)d_in[9];
  const float* bi     = (const float*)d_in[10];
  float* out = (float*)d_out;

  float* ws  = (float*)d_ws;
  float* f   = ws;                             // 131072 f32
  float* y   = ws + 131072;                    // 131072 f32
  unsigned short* W1Ts = (unsigned short*)(ws + 262144);  // 131072 bf16

  k_prep  <<<512,   256, 0, stream>>>(W1, W1Ts, out);
  k_scores<<<NBLKS, 256, 0, stream>>>(X, W1Ts, b1, w2, b2, Wc, f, y);
  k_select<<<16,   1024, 0, stream>>>(f, y, mask, labels, bc, X, Wi, bi, out);
}

// Round 18
// 171.244 us; speedup vs baseline: 1.7734x; 1.7734x over previous
//
#include <hip/hip_runtime.h>
#include <hip/hip_bf16.h>

#define BB 8
#define NN 16384
#define DD 1024
#define AA 128
#define ROWS 64
#define NBLKS (BB * NN / ROWS)   // 2048

typedef __attribute__((ext_vector_type(8))) short bf16x8;
typedef __attribute__((ext_vector_type(4))) float f32x4;
typedef __attribute__((ext_vector_type(4))) unsigned short u16x4;

__device__ __forceinline__ unsigned short f2bf(float x) {
  union { __hip_bfloat16 h; unsigned short u; } cv;
  cv.h = __float2bfloat16(x);
  return cv.u;
}

__device__ __forceinline__ float softplusf(float x) {
  return fmaxf(x, 0.f) + log1pf(expf(-fabsf(x)));
}

// order-preserving float->uint map (monotone)
__device__ __forceinline__ unsigned int ordu(float x) {
  unsigned int u = __float_as_uint(x);
  return (u & 0x80000000u) ? ~u : (u | 0x80000000u);
}

// LDS index swizzle for k_select
__device__ __forceinline__ int fvx(int i) {
  return i ^ ((i >> 6) & 63);
}

// async global->LDS DMA, 16 B per lane; dest resolves to wave base + lane*16
__device__ __forceinline__ void gload16(const void* g, void* l) {
  __builtin_amdgcn_global_load_lds(
      (const __attribute__((address_space(1))) unsigned int*)g,
      (__attribute__((address_space(3))) unsigned int*)l, 16, 0, 0);
}

// ---------------------------------------------------------------------------
// Kernel 0: W1 -> W1Ts bf16 panels (linear image == swizzled Bs layout);
// zero out[8..9].
// ---------------------------------------------------------------------------
__global__ __launch_bounds__(256) void k_prep(
    const float* __restrict__ W1, unsigned short* __restrict__ W1Ts,
    float* __restrict__ out) {
  const int gid = blockIdx.x * 256 + threadIdx.x;
  if (gid == 0) { out[8] = 0.f; out[9] = 0.f; }
  if (gid < DD * AA) {
    const int k = gid >> 7, col = gid & 127;
    const int kp = k >> 6, kin = k & 63;
    const int g = kin >> 3, j = kin & 7;
    W1Ts[kp * 8192 + col * 64 + ((g ^ (col & 7)) << 3) + j] =
        f2bf(W1[k * AA + col]);
  }
}

// ---------------------------------------------------------------------------
// Kernel 1: f[n] = b2 + sum_a w2[a] tanh((X W1)[n][a] + b1[a]); y[n]=X[n].Wc
// R16 champion, byte-identical (64-row tile, 2-barrier loop, B via gload_lds).
// ---------------------------------------------------------------------------
__global__ __launch_bounds__(256) void k_scores(
    const float* __restrict__ X, const unsigned short* __restrict__ W1Ts,
    const float* __restrict__ b1, const float* __restrict__ w2,
    const float* __restrict__ b2p, const float* __restrict__ Wc,
    float* __restrict__ f, float* __restrict__ y) {
  __shared__ unsigned short As[ROWS * 64];   // 8 KB, [row][k] bf16 swizzled
  __shared__ unsigned short Bs[128 * 64];    // 16 KB, [col][k] swizzled image
  const int t = threadIdx.x;
  const int lane = t & 63;
  const int wv = t >> 6;
  const int l15 = lane & 15, lg = lane >> 4;
  const size_t row0 = (size_t)blockIdx.x * ROWS;
  const float* Xb = X + row0 * DD;

  f32x4 zero4 = {0.f, 0.f, 0.f, 0.f};
  f32x4 acc[8];
#pragma unroll
  for (int ni = 0; ni < 8; ++ni) acc[ni] = zero4;

  float yp[4];
#pragma unroll
  for (int j = 0; j < 4; ++j) yp[j] = 0.f;

  for (int st = 0; st < 16; ++st) {
    const int k0 = st * 64;
    // ---- B: linear DMA of the pre-swizzled 16 KB panel ----
    {
      const unsigned short* Pp = W1Ts + st * 8192;
#pragma unroll
      for (int q = 0; q < 4; ++q)
        gload16(Pp + ((wv * 4 + q) * 64 + lane) * 8,
                &Bs[((wv * 4 + q) * 64 + lane) * 8]);
    }
    // ---- A: register stage f32 -> cvt -> swizzled ds_write ----
    const int kq = (t & 15) * 4;
    const float4 wc4 = *(const float4*)(Wc + k0 + kq);
#pragma unroll
    for (int j = 0; j < 4; ++j) {
      const int i = t + j * 256;
      const int r = i >> 4;                  // 0..63
      float4 v = *(const float4*)(Xb + (size_t)r * DD + k0 + kq);
      yp[j] += v.x * wc4.x + v.y * wc4.y + v.z * wc4.z + v.w * wc4.w;
      u16x4 p;
      p.x = f2bf(v.x); p.y = f2bf(v.y); p.z = f2bf(v.z); p.w = f2bf(v.w);
      const int idx = r * 64 + (((kq >> 3) ^ (r & 7)) << 3) + (kq & 7);
      *(u16x4*)&As[idx] = p;
    }
    __syncthreads();
    // ---- MFMA: wave covers rows wv*16..+15 x all 128 cols ----
    const int r = wv * 16 + l15;
    const int rx = r & 7;
#pragma unroll
    for (int ks = 0; ks < 2; ++ks) {
      const int chunk = ks * 4 + lg;
      const bf16x8 af = *(const bf16x8*)&As[r * 64 + ((chunk ^ rx) << 3)];
#pragma unroll
      for (int ni = 0; ni < 8; ++ni) {
        const int c = ni * 16 + l15;
        const bf16x8 bg =
            *(const bf16x8*)&Bs[c * 64 + ((chunk ^ (c & 7)) << 3)];
        acc[ni] = __builtin_amdgcn_mfma_f32_16x16x32_bf16(af, bg, acc[ni], 0, 0, 0);
      }
    }
    __syncthreads();
  }

  // y: reduce yp[j] across the 16 lanes sharing each row
#pragma unroll
  for (int j = 0; j < 4; ++j) {
    float s = yp[j];
    s += __shfl_xor(s, 1);
    s += __shfl_xor(s, 2);
    s += __shfl_xor(s, 4);
    s += __shfl_xor(s, 8);
    if ((t & 15) == 0) y[row0 + (t >> 4) + j * 16] = s;
  }

  // f epilogue: wave-local; C row = lg*4+q (global wv*16+...), col = ni*16+l15
  const float b2 = b2p[0];
  float w2c[8], b1c[8];
#pragma unroll
  for (int ni = 0; ni < 8; ++ni) {
    w2c[ni] = w2[ni * 16 + l15];
    b1c[ni] = b1[ni * 16 + l15];
  }
#pragma unroll
  for (int q = 0; q < 4; ++q) {
    float s = 0.f;
#pragma unroll
    for (int ni = 0; ni < 8; ++ni)
      s += w2c[ni] * tanhf(acc[ni][q] + b1c[ni]);
    s += __shfl_xor(s, 1);
    s += __shfl_xor(s, 2);
    s += __shfl_xor(s, 4);
    s += __shfl_xor(s, 8);
    if (l15 == 0) f[row0 + wv * 16 + lg * 4 + q] = s + b2;
  }
}

// ---------------------------------------------------------------------------
// Kernel 2 (fused select+final): 16 blocks = (bag b, mode).
//   mode 0: bag stats (bag_pred, crit_loss) + top-64 + top-in + out losses
//   mode 1: bottom-64 + bottom-in losses
// Mode-0 caches f/mask in registers across its two passes (single L2 read).
// ---------------------------------------------------------------------------
__global__ __launch_bounds__(1024) void k_select(
    const float* __restrict__ f, const float* __restrict__ y,
    const float* __restrict__ mask, const int* __restrict__ labels,
    const float* __restrict__ bc, const float* __restrict__ X,
    const float* __restrict__ Wi, const float* __restrict__ bi,
    float* __restrict__ out) {
  __shared__ unsigned int uv[NN];          // 64 KB, swizzled via fvx()
  __shared__ unsigned int whist[16][256];  // 16 KB wave-private hists
  __shared__ unsigned int selL[64];
  __shared__ unsigned int wq[4];
  __shared__ unsigned int sb[4];
  __shared__ float redf[16];
  __shared__ float redo[16];
  const int t = threadIdx.x;
  const int lane = t & 63, w = t >> 6;
  const int b = blockIdx.x >> 1;
  const int mode = blockIdx.x & 1;
  const float* fb = f + (size_t)b * NN;
  const float* yb = y + (size_t)b * NN;
  const float* kb = mask + (size_t)b * NN;

  if (mode == 0) {
    float fvr[16];
    float mkr[16];
    float mx = -3.0e38f;
#pragma unroll
    for (int ii = 0; ii < 16; ++ii) {
      const int i = t + ii * 1024;
      const float v = fb[i];
      fvr[ii] = v;
      mkr[ii] = kb[i];
      uv[fvx(i)] = ordu(v);
      mx = fmaxf(mx, mkr[ii] > 0.f ? v : -1.0e30f);
    }
#pragma unroll
    for (int s = 1; s < 64; s <<= 1) mx = fmaxf(mx, __shfl_xor(mx, s));
    if (lane == 0) redf[w] = mx;
    __syncthreads();
    float m = redf[0];
#pragma unroll
    for (int q = 1; q < 16; ++q) m = fmaxf(m, redf[q]);
    __syncthreads();

    float se = 0.f, sy = 0.f;
#pragma unroll
    for (int ii = 0; ii < 16; ++ii) {
      const int i = t + ii * 1024;
      if (mkr[ii] > 0.f) {
        const float e = expf(fvr[ii] - m);
        se += e;
        sy += e * yb[i];
      }
    }
#pragma unroll
    for (int s = 1; s < 64; s <<= 1) se += __shfl_xor(se, s);
    if (lane == 0) redf[w] = se;
    __syncthreads();
    float Z = 0.f;
#pragma unroll
    for (int q = 0; q < 16; ++q) Z += redf[q];
    __syncthreads();
#pragma unroll
    for (int s = 1; s < 64; s <<= 1) sy += __shfl_xor(sy, s);
    if (lane == 0) redf[w] = sy;
    __syncthreads();
    if (t == 0) {
      float Sy = 0.f;
#pragma unroll
      for (int q = 0; q < 16; ++q) Sy += redf[q];
      const float bp = Sy / Z + bc[0];
      out[b] = bp;
      const float lf = (float)labels[b];
      atomicAdd(out + 8, (softplusf(bp) - bp * lf) * 0.125f);
    }
  } else {
    for (int i = t; i < NN; i += 1024) uv[fvx(i)] = ~ordu(fb[i]);
  }
  __syncthreads();

  // 4-pass byte radix select for the 64 largest keys (ties: lowest index)
  const int i0 = t * 16;
  unsigned int pref = 0u, above = 0u, krem = 64u;
  for (int p = 3; p >= 0; --p) {
    for (int q = t; q < 4096; q += 1024) ((unsigned int*)whist)[q] = 0u;
    __syncthreads();
    const unsigned int pmask = (p == 3) ? 0u : (0xFFFFFFFFu << ((p + 1) * 8));
    for (int j = 0; j < 16; ++j) {
      const unsigned int u = uv[fvx(i0 + j)];
      if ((u & pmask) == pref)
        atomicAdd(&whist[w][(u >> (p * 8)) & 255u], 1u);
    }
    __syncthreads();
    unsigned int v = 0, s = 0;
    if (t < 256) {
#pragma unroll
      for (int q = 0; q < 16; ++q) v += whist[q][t];
      s = v;
#pragma unroll
      for (int off = 1; off < 64; off <<= 1) {
        const unsigned int o = __shfl_down(s, off);
        if (lane + off < 64) s += o;
      }
      if (lane == 0) wq[w] = s;
    }
    __syncthreads();
    if (t < 256) {
      unsigned int hi = 0;
      for (int q = w + 1; q < 4; ++q) hi += wq[q];
      const unsigned int Ssuf = s + hi;
      const unsigned int Snext = Ssuf - v;
      if (Ssuf >= krem && Snext < krem) {
        sb[0] = pref | ((unsigned int)t << (p * 8));
        sb[1] = above + Snext;
        sb[2] = krem - Snext;
        sb[3] = 0u;
      }
    }
    __syncthreads();
    pref = sb[0]; above = sb[1]; krem = sb[2];
  }
  unsigned int myt = 0;
  for (int j = 0; j < 16; ++j) {
    const unsigned int u = uv[fvx(i0 + j)];
    if (u > pref) {
      const unsigned int pos = atomicAdd(&sb[3], 1u);
      selL[pos] = i0 + j;
    } else if (u == pref) {
      myt++;
    }
  }
  unsigned int pv = myt;
#pragma unroll
  for (int o2 = 1; o2 < 64; o2 <<= 1) {
    const unsigned int o = __shfl_up(pv, o2);
    if (lane >= o2) pv += o;
  }
  __syncthreads();
  if (lane == 63) ((unsigned int*)whist)[w] = pv;   // reuse whist
  __syncthreads();
  unsigned int base = 0;
  for (int q = 0; q < w; ++q) base += ((unsigned int*)whist)[q];
  unsigned int gg = base + pv - myt;
  for (int j = 0; j < 16 && myt > 0; ++j) {
    const unsigned int u = uv[fvx(i0 + j)];
    if (u == pref) {
      if (gg < krem) selL[above + gg] = i0 + j;
      gg++;
      myt--;
    }
  }
  __syncthreads();

  // ---- fused instance losses for this block's 64 rows ----
  const int label = labels[b];
  const float* Win = Wi + label * (DD * 2);
  const float* Wot = Wi + (1 - label) * (DD * 2);
  const float bin0 = bi[label * 2], bin1 = bi[label * 2 + 1];
  const float bo0 = bi[(1 - label) * 2], bo1 = bi[(1 - label) * 2 + 1];
  float ain = 0.f, aout = 0.f;
  for (int rr = w; rr < 64; rr += 16) {     // 4 rows per wave
    const int id = selL[rr];
    const float* xr = X + ((size_t)b * NN + id) * DD;
    float p0 = 0.f, p1 = 0.f, p2 = 0.f, p3 = 0.f;
#pragma unroll
    for (int j = 0; j < 16; j += 4) {
      const int d = lane * 16 + j;
      const float4 x = *(const float4*)(xr + d);
      const float4 wa = *(const float4*)(Win + d * 2);
      const float4 wb = *(const float4*)(Win + d * 2 + 4);
      p0 += x.x * wa.x + x.y * wa.z + x.z * wb.x + x.w * wb.z;
      p1 += x.x * wa.y + x.y * wa.w + x.z * wb.y + x.w * wb.w;
      if (mode == 0) {
        const float4 oa = *(const float4*)(Wot + d * 2);
        const float4 ob = *(const float4*)(Wot + d * 2 + 4);
        p2 += x.x * oa.x + x.y * oa.z + x.z * ob.x + x.w * ob.z;
        p3 += x.x * oa.y + x.y * oa.w + x.z * ob.y + x.w * ob.w;
      }
    }
#pragma unroll
    for (int sh = 1; sh < 64; sh <<= 1) {
      p0 += __shfl_xor(p0, sh);
      p1 += __shfl_xor(p1, sh);
      p2 += __shfl_xor(p2, sh);
      p3 += __shfl_xor(p3, sh);
    }
    if (lane == 0) {
      const float l0 = p0 + bin0, l1 = p1 + bin1;
      if (mode == 0) {
        ain += softplusf(l0 + 1.f - l1);              // top, target 1
        aout += softplusf((p3 + bo1) + 1.f - (p2 + bo0));  // out, target 0
      } else {
        ain += softplusf(l1 + 1.f - l0);              // bottom, target 0
      }
    }
  }
  if (lane == 0) { redf[w] = ain; redo[w] = aout; }
  __syncthreads();
  if (t == 0) {
    float ti = 0.f, to = 0.f;
#pragma unroll
    for (int q = 0; q < 16; ++q) { ti += redf[q]; to += redo[q]; }
    atomicAdd(out + 9, ti * (1.0f / 128.0f) + to * (1.0f / 64.0f));
  }
}

// ---------------------------------------------------------------------------

extern "C" void kernel_launch(void* const* d_in, const int* in_sizes, int n_in,
                              void* d_out, int out_size, void* d_ws, size_t ws_size,
                              hipStream_t stream) {
  const float* X      = (const float*)d_in[0];
  const float* mask   = (const float*)d_in[1];
  const int*   labels = (const int*)d_in[2];
  const float* W1     = (const float*)d_in[3];
  const float* b1     = (const float*)d_in[4];
  const float* w2     = (const float*)d_in[5];
  const float* b2     = (const float*)d_in[6];
  const float* Wc     = (const float*)d_in[7];
  const float* bc     = (const float*)d_in[8];
  const float* Wi     = (const float*)d_in[9];
  const float* bi     = (const float*)d_in[10];
  float* out = (float*)d_out;

  float* ws  = (float*)d_ws;
  float* f   = ws;                             // 131072 f32
  float* y   = ws + 131072;                    // 131072 f32
  unsigned short* W1Ts = (unsigned short*)(ws + 262144);  // 131072 bf16

  k_prep  <<<512,   256, 0, stream>>>(W1, W1Ts, out);
  k_scores<<<NBLKS, 256, 0, stream>>>(X, W1Ts, b1, w2, b2, Wc, f, y);
  k_select<<<16,   1024, 0, stream>>>(f, y, mask, labels, bc, X, Wi, bi, out);
}